// Round 18
// baseline (158.992 us; speedup 1.0000x reference)
//
#include <hip/hip_runtime.h>

#define L_SEQ 2048
#define KDIM  512

typedef __attribute__((ext_vector_type(8))) short short8v;   // 8 x bf16
typedef __attribute__((ext_vector_type(4))) float f32x4;
typedef __attribute__((ext_vector_type(16))) float f32x16;
typedef __attribute__((ext_vector_type(4))) unsigned u32x4;

static __device__ __forceinline__ short f2b(float f) {
    union { float f; unsigned u; } v; v.f = f;
    unsigned r = v.u + 0x7fffu + ((v.u >> 16) & 1u);
    return (short)(r >> 16);
}

static __device__ __forceinline__ float fast_exp2(float x) {
#if __has_builtin(__builtin_amdgcn_exp2f)
    return __builtin_amdgcn_exp2f(x);
#else
    return exp2f(x);
#endif
}

// async global->LDS DMA, 16B per lane. LDS side is wave-uniform base + lane*16.
static __device__ __forceinline__ void gl2lds16(const short* g, short* l) {
    __builtin_amdgcn_global_load_lds(
        (const __attribute__((address_space(1))) unsigned*)g,
        (__attribute__((address_space(3))) unsigned*)l,
        16, 0, 0);
}

// ---------------------------------------------------------------------------
// prep: (blocks 0..1023)  w_qkv + w_out fp32 -> bf16
//       (blocks 1024..2047) x [b][c][l] fp32 -> xT [b][l][c] bf16
// ---------------------------------------------------------------------------
__global__ __launch_bounds__(256) void prep(
    const float* __restrict__ wq, const float* __restrict__ wo,
    const float* __restrict__ x,
    short* __restrict__ wqb, short* __restrict__ wob, short* __restrict__ xT)
{
    __shared__ __align__(16) float T[64 * 72];
    const int t = threadIdx.x;
    int bid = blockIdx.x;

    if (bid < 1024) {
        const int i = bid * 256 + t;               // float4 index
        const int NQ = 1536 * 512 / 4;
        float4 v;
        if (i < NQ) v = ((const float4*)wq)[i];
        else        v = ((const float4*)wo)[i - NQ];
        short4 s;
        s.x = f2b(v.x); s.y = f2b(v.y); s.z = f2b(v.z); s.w = f2b(v.w);
        if (i < NQ) ((short4*)wqb)[i] = s;
        else        ((short4*)wob)[i - NQ] = s;
        return;
    }
    bid -= 1024;
    const int l0 = (bid & 31) * 64;
    const int c0 = ((bid >> 5) & 7) * 64;
    const int b  = bid >> 8;

#pragma unroll
    for (int j = 0; j < 4; ++j) {
        const int idx = j * 256 + t;
        const int row = idx >> 4, c4 = idx & 15;
        const float4 v = *(const float4*)&x[((size_t)b * KDIM + c0 + row) * L_SEQ + l0 + c4 * 4];
        *(float4*)&T[row * 72 + c4 * 4] = v;
    }
    __syncthreads();

#pragma unroll
    for (int j = 0; j < 2; ++j) {
        const int idx = j * 256 + t;
        const int l = idx >> 3, ch = idx & 7;
        short8v s;
#pragma unroll
        for (int e = 0; e < 8; ++e)
            s[e] = f2b(T[(ch * 8 + e) * 72 + l]);
        *(short8v*)&xT[((size_t)b * L_SEQ + l0 + l) * KDIM + c0 + ch * 8] = s;
    }
}

// ---------------------------------------------------------------------------
// m97-style MFMA "bt" GEMM: C[o][l] = sum_c A[o][c]*B[l][c], bf16 row-major.
// Unpadded LDS tiles, global_load_lds(16B) staging, BK=64.
// 1D grid + bijective XCD-chunked swizzle (T1, verified round 15).
// EPI 0: tile 128x128 -> QKV epilogue (Q/K [bh][l][d] q-scaled, V [bh][d][l]).
// EPI 1: tile  64x128 -> fp32 C[b][o][l] + bias.
// ---------------------------------------------------------------------------
template<int EPI>
__global__ __launch_bounds__(256) void gemm_bt(
    const short* __restrict__ Ag, const short* __restrict__ Bbase,
    const float* __restrict__ bias,
    short* __restrict__ Qws, short* __restrict__ Kws, short* __restrict__ Vws,
    float* __restrict__ Cout)
{
    constexpr int TO   = (EPI == 0) ? 128 : 64;   // o-tile
    constexpr int WO   = TO / 2;                  // per-wave o
    constexpr int NI   = WO / 16;                 // i-subtiles per wave
    constexpr int CA   = TO * 64 * 2 / 1024;      // A chunks (1KB each)
    constexpr int CB   = 16;                      // B chunks
    constexpr int CPW  = (CA + CB) / 4;           // chunks per wave
    constexpr int SMEM = (EPI == 0) ? 34816 : 24576;
    constexpr int NY   = (EPI == 0) ? 12 : 8;     // o-tiles
    constexpr int CPX  = 16 * NY * 4 / 8;         // blocks per XCD chunk

    // XCD-chunked bijective swizzle (grid size = 8*CPX exactly)
    const int o   = blockIdx.x;
    const int wsw = (o & 7) * CPX + (o >> 3);
    const int xb  = wsw / (NY * 4);
    const int rem = wsw % (NY * 4);
    const int bz  = rem / NY;
    const int yb  = rem % NY;

    const int o0 = yb * TO;
    const int l0 = xb * 128;
    const short* Bg = Bbase + (size_t)bz * L_SEQ * KDIM;

    __shared__ __align__(16) char smem[SMEM];
    short* sA = (short*)smem;                       // [TO][64] unpadded
    short* sB = (short*)(smem + TO * 64 * 2);       // [128][64] unpadded

    const int t    = threadIdx.x;
    const int w    = t >> 6;
    const int lane = t & 63;
    const int quad = lane >> 4;
    const int l16  = lane & 15;
    const int wo   = (w & 1) * WO;
    const int wl   = (w >> 1) * 64;

    f32x4 acc[NI][4];
#pragma unroll
    for (int i = 0; i < NI; ++i)
#pragma unroll
        for (int n = 0; n < 4; ++n) acc[i][n] = (f32x4){0,0,0,0};

    const int lrow = lane >> 3;          // 0..7 within a chunk
    const int lcol = (lane & 7) * 8;     // 8-short column offset

    for (int k0 = 0; k0 < KDIM; k0 += 64) {
#pragma unroll
        for (int p = 0; p < CPW; ++p) {
            const int cid = w * CPW + p;
            if (cid < CA) {
                const int row = cid * 8 + lrow;
                gl2lds16(Ag + (size_t)(o0 + row) * KDIM + k0 + lcol, sA + cid * 512);
            } else {
                const int row = (cid - CA) * 8 + lrow;
                gl2lds16(Bg + (size_t)(l0 + row) * KDIM + k0 + lcol, sB + (cid - CA) * 512);
            }
        }
        __syncthreads();

#pragma unroll
        for (int ks = 0; ks < 2; ++ks) {
            short8v af[NI], bf[4];
#pragma unroll
            for (int i = 0; i < NI; ++i)
                af[i] = *(const short8v*)&sA[(wo + i * 16 + l16) * 64 + ks * 32 + quad * 8];
#pragma unroll
            for (int n = 0; n < 4; ++n)
                bf[n] = *(const short8v*)&sB[(wl + n * 16 + l16) * 64 + ks * 32 + quad * 8];
#pragma unroll
            for (int i = 0; i < NI; ++i)
#pragma unroll
                for (int n = 0; n < 4; ++n)
                    acc[i][n] = __builtin_amdgcn_mfma_f32_16x16x32_bf16(af[i], bf[n], acc[i][n], 0, 0, 0);
        }
        __syncthreads();
    }

    if (EPI == 0) {
        const int type  = o0 >> 9;              // 0=q 1=k 2=v
        const int local = o0 & 511;
        const int bh0   = bz * 8 + (local >> 6);
        // q pre-scaled by DIM_HEAD^-0.5 * log2(e) so attention can use exp2
        const float sc  = (type == 0) ? 0.18033688011112042f : 1.0f;
        short* T = (short*)smem;     // [128][136] = 34816 B

        if (type == 2) {
#pragma unroll
            for (int i = 0; i < NI; ++i)
#pragma unroll
            for (int n = 0; n < 4; ++n)
#pragma unroll
                    for (int r = 0; r < 4; ++r)
                        T[(wo + i * 16 + quad * 4 + r) * 136 + wl + n * 16 + l16] =
                            f2b(acc[i][n][r]);
            __syncthreads();
#pragma unroll
            for (int p = 0; p < 8; ++p) {
                const int idx = p * 256 + t;
                const int oo = idx >> 4, cc = idx & 15;
                const float4 v = *(const float4*)&T[oo * 136 + cc * 8];
                short* dst = Vws + ((size_t)(bh0 + (oo >> 6)) * 64 + (oo & 63)) * L_SEQ + l0 + cc * 8;
                *(float4*)dst = v;
            }
        } else {
#pragma unroll
            for (int i = 0; i < NI; ++i)
#pragma unroll
                for (int n = 0; n < 4; ++n) {
                    short4 s;
                    s.x = f2b(acc[i][n][0] * sc);
                    s.y = f2b(acc[i][n][1] * sc);
                    s.z = f2b(acc[i][n][2] * sc);
                    s.w = f2b(acc[i][n][3] * sc);
                    *(short4*)&T[(wl + n * 16 + l16) * 136 + wo + i * 16 + quad * 4] = s;
                }
            __syncthreads();
            short* base = (type == 0) ? Qws : Kws;
#pragma unroll
            for (int p = 0; p < 8; ++p) {
                const int idx = p * 256 + t;
                const int l = idx >> 4, cc = idx & 15;
                const float4 v = *(const float4*)&T[l * 136 + cc * 8];
                short* dst = base + ((size_t)(bh0 + (cc >> 3)) * L_SEQ + l0 + l) * 64 + (cc & 7) * 8;
                *(float4*)dst = v;
            }
        }
    } else {
        float* Cb = Cout + (size_t)bz * KDIM * L_SEQ;
#pragma unroll
        for (int i = 0; i < NI; ++i) {
            const int oo = o0 + wo + i * 16 + quad * 4;
            float bv[4];
#pragma unroll
            for (int r = 0; r < 4; ++r) bv[r] = bias[oo + r];
#pragma unroll
            for (int n = 0; n < 4; ++n) {
                const int l = l0 + wl + n * 16 + l16;
#pragma unroll
                for (int r = 0; r < 4; ++r)
                    Cb[(size_t)(oo + r) * L_SEQ + l] = acc[i][n][r] + bv[r];
            }
        }
    }
}

// ---------------------------------------------------------------------------
// MFMA attention v6: v4's frag math with 64-ROW WAVES (2 MFMA per frag read).
// Round-15 pipe budget: DS was the top pipe (~55%) because each 32x32 MFMA
// consumed one fresh b128 fragment (12cyc read vs 8cyc MFMA). Fix: 4 waves
// of 256 threads, each owning 64 i x 32 j (gi in {0,1} x jh in {0,1}). Q is
// register-resident (qa[2][4]) so widening i is LDS-free: each K-frag feeds
// 2 QK MFMAs (it=0,1), each V-frag feeds 2 PV MFMAs. DS/CU/tile 1900->~1150,
// balancing DS/MFMA/VALU at ~1100-1240 each. Occupancy 16->8 waves/CU but
// per-wave ILP doubles (2 indep MFMAs per read, 2 S-tiles in softmax).
// Schedule: round-3 verified 2-buffer single-barrier (S-carry dropped: it
// measured null in round 10). P stays in-register via permlane32_swap.
// XCD swizzle bh = id&31.
// ---------------------------------------------------------------------------
static __device__ __forceinline__ void plswap(unsigned& a, unsigned& b) {
    asm("v_permlane32_swap_b32 %0, %1" : "+v"(a), "+v"(b));
}

__global__ __launch_bounds__(256, 2) void attn_mfma(
    const short* __restrict__ Qws, const short* __restrict__ Kws,
    const short* __restrict__ Vws, short* __restrict__ ao)
{
    const int bh = blockIdx.x & 31;
    const int b  = bh >> 3;
    const int h  = bh & 7;
    const int i0 = (blockIdx.x >> 5) * 128;

    __shared__ __align__(16) char smem[36864];
    // buffer p (p=0,1) at byte p*18432: K [64 j][72 d] at 0, V^T [64 d][72 j]
    // at +9216. Epilogue overlays (phase-separated by barriers):
    // Opart 32768B at 0, Rp 512B at 32768, then Old [128][68] f32 at 0.
    float* Old = (float*)smem;

    const int t    = threadIdx.x;
    const int w    = t >> 6;               // 0..3
    const int lane = t & 63;
    const int l31  = lane & 31;
    const int hi   = lane >> 5;            // half-wave
    const int gi   = w >> 1;               // i-group 0..1 (64 rows each)
    const int jh   = w & 1;                // j-half of the 64-j tile

    const short* Qb = Qws + (size_t)bh * L_SEQ * 64;
    const short* Kb = Kws + (size_t)bh * L_SEQ * 64;
    const short* Vb = Vws + (size_t)bh * 64 * L_SEQ;

    // Persistent Q fragments, 2 i-tiles (B-operand: col=i=l31, k=d)
    short8v qa[2][4];
#pragma unroll
    for (int it = 0; it < 2; ++it)
#pragma unroll
        for (int dk = 0; dk < 4; ++dk)
            qa[it][dk] = *(const short8v*)(Qb +
                (size_t)(i0 + gi * 64 + it * 32 + l31) * 64 + dk * 16 + hi * 8);

    // O partials: [it][dh] (i-tile x d-half), 64 VGPR
    f32x16 o00, o01, o10, o11;
#pragma unroll
    for (int e = 0; e < 16; ++e) { o00[e] = 0.f; o01[e] = 0.f; o10[e] = 0.f; o11[e] = 0.f; }
    float rsum0 = 0.f, rsum1 = 0.f;

    const int r = t >> 2, c = t & 3;        // staging: 64 rows x 4 thr (16 shorts each)

    // Prologue: stage tile 0 into buffer 0
    {
        short* K0 = (short*)smem;
        short* V0 = (short*)(smem + 9216);
        const short* kg = Kb + (size_t)r * 64 + c * 16;
        const short* vg = Vb + (size_t)r * L_SEQ + c * 16;
        const float4 k0 = *(const float4*)kg;
        const float4 k1 = *(const float4*)(kg + 8);
        const float4 v0 = *(const float4*)vg;
        const float4 v1 = *(const float4*)(vg + 8);
        *(float4*)&K0[r * 72 + c * 16]     = k0;
        *(float4*)&K0[r * 72 + c * 16 + 8] = k1;
        *(float4*)&V0[r * 72 + c * 16]     = v0;
        *(float4*)&V0[r * 72 + c * 16 + 8] = v1;
    }
    __syncthreads();

    for (int jt = 0; jt < L_SEQ / 64; ++jt) {
        const int j0 = jt * 64;
        const short* Kc = (const short*)(smem + (jt & 1) * 18432);
        const short* Vc = (const short*)(smem + (jt & 1) * 18432 + 9216);
        const bool more = (jt + 1 < L_SEQ / 64);

        // 1. issue next tile's global loads FIRST: latency hides under compute
        float4 nk0, nk1, nv0, nv1;
        if (more) {
            const short* kg = Kb + (size_t)(j0 + 64 + r) * 64 + c * 16;
            const short* vg = Vb + (size_t)r * L_SEQ + j0 + 64 + c * 16;
            nk0 = *(const float4*)kg;
            nk1 = *(const float4*)(kg + 8);
            nv0 = *(const float4*)vg;
            nv1 = *(const float4*)(vg + 8);
        }

        // 2. QK: each kf read feeds BOTH i-tiles (2 MFMA / read)
        f32x16 s0, s1;
#pragma unroll
        for (int e = 0; e < 16; ++e) { s0[e] = 0.f; s1[e] = 0.f; }
#pragma unroll
        for (int dk = 0; dk < 4; ++dk) {
            const short8v kf = *(const short8v*)&Kc[(jh * 32 + l31) * 72 + dk * 16 + hi * 8];
            s0 = __builtin_amdgcn_mfma_f32_32x32x16_bf16(kf, qa[0][dk], s0, 0, 0, 0);
            s1 = __builtin_amdgcn_mfma_f32_32x32x16_bf16(kf, qa[1][dk], s1, 0, 0, 0);
        }

        // 3. softmax + pack + permlane exchange, per i-tile
        short8v pa00, pa01, pa10, pa11;   // [it][ks]
        {
            float p[16];
#pragma unroll
            for (int e = 0; e < 16; ++e) p[e] = fast_exp2(s0[e]);
#pragma unroll
            for (int e = 0; e < 16; e += 4)
                rsum0 += (p[e] + p[e + 1]) + (p[e + 2] + p[e + 3]);
            unsigned wv[8];
#pragma unroll
            for (int g = 0; g < 4; ++g) {
                wv[2 * g]     = __builtin_amdgcn_perm(__float_as_uint(p[4 * g + 1]),
                                                      __float_as_uint(p[4 * g]),     0x07060302u);
                wv[2 * g + 1] = __builtin_amdgcn_perm(__float_as_uint(p[4 * g + 3]),
                                                      __float_as_uint(p[4 * g + 2]), 0x07060302u);
            }
            unsigned a0 = wv[0], a2 = wv[2]; plswap(a0, a2);
            unsigned a1 = wv[1], a3 = wv[3]; plswap(a1, a3);
            unsigned b0 = wv[4], b2 = wv[6]; plswap(b0, b2);
            unsigned b1 = wv[5], b3 = wv[7]; plswap(b1, b3);
            u32x4 f0, f1;
            f0[0] = a0; f0[1] = a1; f0[2] = a2; f0[3] = a3;
            f1[0] = b0; f1[1] = b1; f1[2] = b2; f1[3] = b3;
            pa00 = __builtin_bit_cast(short8v, f0);
            pa01 = __builtin_bit_cast(short8v, f1);
        }
        {
            float p[16];
#pragma unroll
            for (int e = 0; e < 16; ++e) p[e] = fast_exp2(s1[e]);
#pragma unroll
            for (int e = 0; e < 16; e += 4)
                rsum1 += (p[e] + p[e + 1]) + (p[e + 2] + p[e + 3]);
            unsigned wv[8];
#pragma unroll
            for (int g = 0; g < 4; ++g) {
                wv[2 * g]     = __builtin_amdgcn_perm(__float_as_uint(p[4 * g + 1]),
                                                      __float_as_uint(p[4 * g]),     0x07060302u);
                wv[2 * g + 1] = __builtin_amdgcn_perm(__float_as_uint(p[4 * g + 3]),
                                                      __float_as_uint(p[4 * g + 2]), 0x07060302u);
            }
            unsigned a0 = wv[0], a2 = wv[2]; plswap(a0, a2);
            unsigned a1 = wv[1], a3 = wv[3]; plswap(a1, a3);
            unsigned b0 = wv[4], b2 = wv[6]; plswap(b0, b2);
            unsigned b1 = wv[5], b3 = wv[7]; plswap(b1, b3);
            u32x4 f0, f1;
            f0[0] = a0; f0[1] = a1; f0[2] = a2; f0[3] = a3;
            f1[0] = b0; f1[1] = b1; f1[2] = b2; f1[3] = b3;
            pa10 = __builtin_bit_cast(short8v, f0);
            pa11 = __builtin_bit_cast(short8v, f1);
        }

        // 4. PV: each vf read feeds BOTH i-tiles (2 MFMA / read)
        {
            const short8v v00 = *(const short8v*)&Vc[(0 * 32 + l31) * 72 + jh * 32 + 0 * 16 + hi * 8];
            o00 = __builtin_amdgcn_mfma_f32_32x32x16_bf16(pa00, v00, o00, 0, 0, 0);
            o10 = __builtin_amdgcn_mfma_f32_32x32x16_bf16(pa10, v00, o10, 0, 0, 0);
            const short8v v10 = *(const short8v*)&Vc[(1 * 32 + l31) * 72 + jh * 32 + 0 * 16 + hi * 8];
            o01 = __builtin_amdgcn_mfma_f32_32x32x16_bf16(pa00, v10, o01, 0, 0, 0);
            o11 = __builtin_amdgcn_mfma_f32_32x32x16_bf16(pa10, v10, o11, 0, 0, 0);
            const short8v v01 = *(const short8v*)&Vc[(0 * 32 + l31) * 72 + jh * 32 + 1 * 16 + hi * 8];
            o00 = __builtin_amdgcn_mfma_f32_32x32x16_bf16(pa01, v01, o00, 0, 0, 0);
            o10 = __builtin_amdgcn_mfma_f32_32x32x16_bf16(pa11, v01, o10, 0, 0, 0);
            const short8v v11 = *(const short8v*)&Vc[(1 * 32 + l31) * 72 + jh * 32 + 1 * 16 + hi * 8];
            o01 = __builtin_amdgcn_mfma_f32_32x32x16_bf16(pa01, v11, o01, 0, 0, 0);
            o11 = __builtin_amdgcn_mfma_f32_32x32x16_bf16(pa11, v11, o11, 0, 0, 0);
        }

        // 5. drain prefetch into the other buffer; single per-tile barrier
        if (more) {
            short* Kn = (short*)(smem + ((jt & 1) ^ 1) * 18432);
            short* Vn = (short*)(smem + ((jt & 1) ^ 1) * 18432 + 9216);
            *(float4*)&Kn[r * 72 + c * 16]     = nk0;
            *(float4*)&Kn[r * 72 + c * 16 + 8] = nk1;
            *(float4*)&Vn[r * 72 + c * 16]     = nv0;
            *(float4*)&Vn[r * 72 + c * 16 + 8] = nv1;
        }
        __syncthreads();
    }

    // ---- epilogue: combine j-halves (partner waves w, w^1), normalize ----
    const float r20 = rsum0 + __shfl_xor(rsum0, 32, 64);
    const float r21 = rsum1 + __shfl_xor(rsum1, 32, 64);

    float* Opart = (float*)smem;                 // [gi][16 chunks][64 lanes][4]
    float* Rp    = (float*)(smem + 32768);       // [128]

    if (jh == 1) {
        // 4 f32x16 = 16 float4-chunks per wave
#pragma unroll
        for (int q = 0; q < 4; ++q) {
            float4 c0 = { o00[4 * q], o00[4 * q + 1], o00[4 * q + 2], o00[4 * q + 3] };
            float4 c1 = { o01[4 * q], o01[4 * q + 1], o01[4 * q + 2], o01[4 * q + 3] };
            float4 c2 = { o10[4 * q], o10[4 * q + 1], o10[4 * q + 2], o10[4 * q + 3] };
            float4 c3 = { o11[4 * q], o11[4 * q + 1], o11[4 * q + 2], o11[4 * q + 3] };
            *(float4*)&Opart[gi * 4096 + (0 * 4 + q) * 256 + lane * 4]  = c0;
            *(float4*)&Opart[gi * 4096 + (1 * 4 + q) * 256 + lane * 4]  = c1;
            *(float4*)&Opart[gi * 4096 + (2 * 4 + q) * 256 + lane * 4]  = c2;
            *(float4*)&Opart[gi * 4096 + (3 * 4 + q) * 256 + lane * 4]  = c3;
        }
        if (hi == 0) {
            Rp[gi * 64 + l31]      = r20;
            Rp[gi * 64 + 32 + l31] = r21;
        }
    }
    __syncthreads();

    if (jh == 0) {
#pragma unroll
        for (int q = 0; q < 4; ++q) {
            const float4 c0 = *(const float4*)&Opart[gi * 4096 + (0 * 4 + q) * 256 + lane * 4];
            const float4 c1 = *(const float4*)&Opart[gi * 4096 + (1 * 4 + q) * 256 + lane * 4];
            const float4 c2 = *(const float4*)&Opart[gi * 4096 + (2 * 4 + q) * 256 + lane * 4];
            const float4 c3 = *(const float4*)&Opart[gi * 4096 + (3 * 4 + q) * 256 + lane * 4];
            o00[4 * q] += c0.x; o00[4 * q + 1] += c0.y; o00[4 * q + 2] += c0.z; o00[4 * q + 3] += c0.w;
            o01[4 * q] += c1.x; o01[4 * q + 1] += c1.y; o01[4 * q + 2] += c1.z; o01[4 * q + 3] += c1.w;
            o10[4 * q] += c2.x; o10[4 * q + 1] += c2.y; o10[4 * q + 2] += c2.z; o10[4 * q + 3] += c2.w;
            o11[4 * q] += c3.x; o11[4 * q + 1] += c3.y; o11[4 * q + 2] += c3.z; o11[4 * q + 3] += c3.w;
        }
        const float inv0 = 1.0014f / (r20 + Rp[gi * 64 + l31]);        // truncation comp.
        const float inv1 = 1.0014f / (r21 + Rp[gi * 64 + 32 + l31]);
#pragma unroll
        for (int e = 0; e < 16; ++e) {
            const int rowi = (e & 3) + 8 * (e >> 2) + 4 * hi;
            const float iv0 = __shfl(inv0, rowi, 64);
            const float iv1 = __shfl(inv1, rowi, 64);
            o00[e] *= iv0;  o01[e] *= iv0;
            o10[e] *= iv1;  o11[e] *= iv1;
        }
    }
    __syncthreads();   // Opart reads done before Old overlay writes

    if (jh == 0) {
#pragma unroll
        for (int e = 0; e < 16; ++e) {
            const int rowi = (e & 3) + 8 * (e >> 2) + 4 * hi;
            Old[(gi * 64 + rowi) * 68 + l31]           = o00[e];
            Old[(gi * 64 + rowi) * 68 + 32 + l31]      = o01[e];
            Old[(gi * 64 + 32 + rowi) * 68 + l31]      = o10[e];
            Old[(gi * 64 + 32 + rowi) * 68 + 32 + l31] = o11[e];
        }
    }
    __syncthreads();

    // vectorized bf16 store: 128 i x 16 float4-cols, 256 threads -> 8 rounds
#pragma unroll
    for (int p = 0; p < 8; ++p) {
        const int idx = p * 256 + t;
        const int i = idx >> 4, c4 = idx & 15;
        const float4 v = *(const float4*)&Old[i * 68 + c4 * 4];
        short4 s;
        s.x = f2b(v.x); s.y = f2b(v.y); s.z = f2b(v.z); s.w = f2b(v.w);
        *(short4*)&ao[((size_t)b * L_SEQ + i0 + i) * KDIM + h * 64 + c4 * 4] = s;
    }
}

// ---------------------------------------------------------------------------
extern "C" void kernel_launch(void* const* d_in, const int* in_sizes, int n_in,
                              void* d_out, int out_size, void* d_ws, size_t ws_size,
                              hipStream_t stream)
{
    const float* x     = (const float*)d_in[0];   // [4][512][2048]
    const float* w_qkv = (const float*)d_in[1];   // [1536][512]
    const float* w_out = (const float*)d_in[2];   // [512][512]
    const float* b_out = (const float*)d_in[3];   // [512]
    float* out = (float*)d_out;                   // [4][512][2048]

    char* ws = (char*)d_ws;
    short* xT    = (short*)ws;                      ws += (size_t)4 * L_SEQ * KDIM * 2;
    short* wq_bf = (short*)ws;                      ws += (size_t)1536 * 512 * 2;
    short* wo_bf = (short*)ws;                      ws += (size_t)512 * 512 * 2;
    short* Qws   = (short*)ws;                      ws += (size_t)32 * L_SEQ * 64 * 2;
    short* Kws   = (short*)ws;                      ws += (size_t)32 * L_SEQ * 64 * 2;
    short* Vws   = (short*)ws;                      ws += (size_t)32 * L_SEQ * 64 * 2;
    short* ao    = (short*)ws;

    dim3 blk(256);
    prep       <<<dim3(2048), blk, 0, stream>>>(w_qkv, w_out, x, wq_bf, wo_bf, xT);
    gemm_bt<0> <<<dim3(768), blk, 0, stream>>>(wq_bf, xT, nullptr, Qws, Kws, Vws, nullptr);
    attn_mfma  <<<dim3(512), blk, 0, stream>>>(Qws, Kws, Vws, ao);
    gemm_bt<1> <<<dim3(512), blk, 0, stream>>>(wo_bf, ao, b_out, nullptr, nullptr, nullptr, out);
}

// Round 19
// 157.910 us; speedup vs baseline: 1.0069x; 1.0069x over previous
//
#include <hip/hip_runtime.h>

#define L_SEQ 2048
#define KDIM  512

typedef __attribute__((ext_vector_type(8))) short short8v;   // 8 x bf16
typedef __attribute__((ext_vector_type(4))) float f32x4;
typedef __attribute__((ext_vector_type(16))) float f32x16;
typedef __attribute__((ext_vector_type(4))) unsigned u32x4;

static __device__ __forceinline__ short f2b(float f) {
    union { float f; unsigned u; } v; v.f = f;
    unsigned r = v.u + 0x7fffu + ((v.u >> 16) & 1u);
    return (short)(r >> 16);
}

static __device__ __forceinline__ float fast_exp2(float x) {
#if __has_builtin(__builtin_amdgcn_exp2f)
    return __builtin_amdgcn_exp2f(x);
#else
    return exp2f(x);
#endif
}

// async global->LDS DMA, 16B per lane. LDS side is wave-uniform base + lane*16.
static __device__ __forceinline__ void gl2lds16(const short* g, short* l) {
    __builtin_amdgcn_global_load_lds(
        (const __attribute__((address_space(1))) unsigned*)g,
        (__attribute__((address_space(3))) unsigned*)l,
        16, 0, 0);
}

// ---------------------------------------------------------------------------
// prep: (blocks 0..1023)  w_qkv + w_out fp32 -> bf16
//       (blocks 1024..2047) x [b][c][l] fp32 -> xT [b][l][c] bf16
// ---------------------------------------------------------------------------
__global__ __launch_bounds__(256) void prep(
    const float* __restrict__ wq, const float* __restrict__ wo,
    const float* __restrict__ x,
    short* __restrict__ wqb, short* __restrict__ wob, short* __restrict__ xT)
{
    __shared__ __align__(16) float T[64 * 72];
    const int t = threadIdx.x;
    int bid = blockIdx.x;

    if (bid < 1024) {
        const int i = bid * 256 + t;               // float4 index
        const int NQ = 1536 * 512 / 4;
        float4 v;
        if (i < NQ) v = ((const float4*)wq)[i];
        else        v = ((const float4*)wo)[i - NQ];
        short4 s;
        s.x = f2b(v.x); s.y = f2b(v.y); s.z = f2b(v.z); s.w = f2b(v.w);
        if (i < NQ) ((short4*)wqb)[i] = s;
        else        ((short4*)wob)[i - NQ] = s;
        return;
    }
    bid -= 1024;
    const int l0 = (bid & 31) * 64;
    const int c0 = ((bid >> 5) & 7) * 64;
    const int b  = bid >> 8;

#pragma unroll
    for (int j = 0; j < 4; ++j) {
        const int idx = j * 256 + t;
        const int row = idx >> 4, c4 = idx & 15;
        const float4 v = *(const float4*)&x[((size_t)b * KDIM + c0 + row) * L_SEQ + l0 + c4 * 4];
        *(float4*)&T[row * 72 + c4 * 4] = v;
    }
    __syncthreads();

#pragma unroll
    for (int j = 0; j < 2; ++j) {
        const int idx = j * 256 + t;
        const int l = idx >> 3, ch = idx & 7;
        short8v s;
#pragma unroll
        for (int e = 0; e < 8; ++e)
            s[e] = f2b(T[(ch * 8 + e) * 72 + l]);
        *(short8v*)&xT[((size_t)b * L_SEQ + l0 + l) * KDIM + c0 + ch * 8] = s;
    }
}

// ---------------------------------------------------------------------------
// m97-style MFMA "bt" GEMM: C[o][l] = sum_c A[o][c]*B[l][c], bf16 row-major.
// Unpadded LDS tiles, global_load_lds(16B) staging, BK=64.
// 1D grid + bijective XCD-chunked swizzle (T1): work linearized y-fastest
// (w = x*NY*4 + z*NY + y) and wgid = (o%8)*CPX + o/8, so each XCD owns a
// contiguous l-column chunk: per-XCD L2 set = B-slice (~1MB) + A (<=1.5MB)
// < 4MB, instead of every XCD touching the full 4MB B panel.
// EPI 0: tile 128x128 -> QKV epilogue (Q/K [bh][l][d] q-scaled, V [bh][d][l]).
// EPI 1: tile  64x128 -> fp32 C[b][o][l] + bias.
// ---------------------------------------------------------------------------
template<int EPI>
__global__ __launch_bounds__(256) void gemm_bt(
    const short* __restrict__ Ag, const short* __restrict__ Bbase,
    const float* __restrict__ bias,
    short* __restrict__ Qws, short* __restrict__ Kws, short* __restrict__ Vws,
    float* __restrict__ Cout)
{
    constexpr int TO   = (EPI == 0) ? 128 : 64;   // o-tile
    constexpr int WO   = TO / 2;                  // per-wave o
    constexpr int NI   = WO / 16;                 // i-subtiles per wave
    constexpr int CA   = TO * 64 * 2 / 1024;      // A chunks (1KB each)
    constexpr int CB   = 16;                      // B chunks
    constexpr int CPW  = (CA + CB) / 4;           // chunks per wave
    constexpr int SMEM = (EPI == 0) ? 34816 : 24576;
    constexpr int NY   = (EPI == 0) ? 12 : 8;     // o-tiles
    constexpr int CPX  = 16 * NY * 4 / 8;         // blocks per XCD chunk

    // XCD-chunked bijective swizzle (grid size = 8*CPX exactly)
    const int o   = blockIdx.x;
    const int wsw = (o & 7) * CPX + (o >> 3);
    const int xb  = wsw / (NY * 4);
    const int rem = wsw % (NY * 4);
    const int bz  = rem / NY;
    const int yb  = rem % NY;

    const int o0 = yb * TO;
    const int l0 = xb * 128;
    const short* Bg = Bbase + (size_t)bz * L_SEQ * KDIM;

    __shared__ __align__(16) char smem[SMEM];
    short* sA = (short*)smem;                       // [TO][64] unpadded
    short* sB = (short*)(smem + TO * 64 * 2);       // [128][64] unpadded

    const int t    = threadIdx.x;
    const int w    = t >> 6;
    const int lane = t & 63;
    const int quad = lane >> 4;
    const int l16  = lane & 15;
    const int wo   = (w & 1) * WO;
    const int wl   = (w >> 1) * 64;

    f32x4 acc[NI][4];
#pragma unroll
    for (int i = 0; i < NI; ++i)
#pragma unroll
        for (int n = 0; n < 4; ++n) acc[i][n] = (f32x4){0,0,0,0};

    const int lrow = lane >> 3;          // 0..7 within a chunk
    const int lcol = (lane & 7) * 8;     // 8-short column offset

    for (int k0 = 0; k0 < KDIM; k0 += 64) {
#pragma unroll
        for (int p = 0; p < CPW; ++p) {
            const int cid = w * CPW + p;
            if (cid < CA) {
                const int row = cid * 8 + lrow;
                gl2lds16(Ag + (size_t)(o0 + row) * KDIM + k0 + lcol, sA + cid * 512);
            } else {
                const int row = (cid - CA) * 8 + lrow;
                gl2lds16(Bg + (size_t)(l0 + row) * KDIM + k0 + lcol, sB + (cid - CA) * 512);
            }
        }
        __syncthreads();

#pragma unroll
        for (int ks = 0; ks < 2; ++ks) {
            short8v af[NI], bf[4];
#pragma unroll
            for (int i = 0; i < NI; ++i)
                af[i] = *(const short8v*)&sA[(wo + i * 16 + l16) * 64 + ks * 32 + quad * 8];
#pragma unroll
            for (int n = 0; n < 4; ++n)
                bf[n] = *(const short8v*)&sB[(wl + n * 16 + l16) * 64 + ks * 32 + quad * 8];
#pragma unroll
            for (int i = 0; i < NI; ++i)
#pragma unroll
                for (int n = 0; n < 4; ++n)
                    acc[i][n] = __builtin_amdgcn_mfma_f32_16x16x32_bf16(af[i], bf[n], acc[i][n], 0, 0, 0);
        }
        __syncthreads();
    }

    if (EPI == 0) {
        const int type  = o0 >> 9;              // 0=q 1=k 2=v
        const int local = o0 & 511;
        const int bh0   = bz * 8 + (local >> 6);
        // q pre-scaled by DIM_HEAD^-0.5 * log2(e) so attention can use exp2
        const float sc  = (type == 0) ? 0.18033688011112042f : 1.0f;
        short* T = (short*)smem;     // [128][136] = 34816 B

        if (type == 2) {
#pragma unroll
            for (int i = 0; i < NI; ++i)
#pragma unroll
                for (int n = 0; n < 4; ++n)
#pragma unroll
                    for (int r = 0; r < 4; ++r)
                        T[(wo + i * 16 + quad * 4 + r) * 136 + wl + n * 16 + l16] =
                            f2b(acc[i][n][r]);
            __syncthreads();
#pragma unroll
            for (int p = 0; p < 8; ++p) {
                const int idx = p * 256 + t;
                const int oo = idx >> 4, cc = idx & 15;
                const float4 v = *(const float4*)&T[oo * 136 + cc * 8];
                short* dst = Vws + ((size_t)(bh0 + (oo >> 6)) * 64 + (oo & 63)) * L_SEQ + l0 + cc * 8;
                *(float4*)dst = v;
            }
        } else {
#pragma unroll
            for (int i = 0; i < NI; ++i)
#pragma unroll
                for (int n = 0; n < 4; ++n) {
                    short4 s;
                    s.x = f2b(acc[i][n][0] * sc);
                    s.y = f2b(acc[i][n][1] * sc);
                    s.z = f2b(acc[i][n][2] * sc);
                    s.w = f2b(acc[i][n][3] * sc);
                    *(short4*)&T[(wl + n * 16 + l16) * 136 + wo + i * 16 + quad * 4] = s;
                }
            __syncthreads();
            short* base = (type == 0) ? Qws : Kws;
#pragma unroll
            for (int p = 0; p < 8; ++p) {
                const int idx = p * 256 + t;
                const int l = idx >> 4, cc = idx & 15;
                const float4 v = *(const float4*)&T[l * 136 + cc * 8];
                short* dst = base + ((size_t)(bh0 + (cc >> 3)) * L_SEQ + l0 + l) * 64 + (cc & 7) * 8;
                *(float4*)dst = v;
            }
        }
    } else {
        float* Cb = Cout + (size_t)bz * KDIM * L_SEQ;
#pragma unroll
        for (int i = 0; i < NI; ++i) {
            const int oo = o0 + wo + i * 16 + quad * 4;
            float bv[4];
#pragma unroll
            for (int r = 0; r < 4; ++r) bv[r] = bias[oo + r];
#pragma unroll
            for (int n = 0; n < 4; ++n) {
                const int l = l0 + wl + n * 16 + l16;
#pragma unroll
                for (int r = 0; r < 4; ++r)
                    Cb[(size_t)(oo + r) * L_SEQ + l] = acc[i][n][r] + bv[r];
            }
        }
    }
}

// ---------------------------------------------------------------------------
// MFMA attention v4 (verified best, 46.1us): 32x32x16 MFMA, j-split waves,
// P fully in-register via v_permlane32_swap_b32, 3-buffer pipeline, one
// barrier per tile. Occupancy/traffic optimum confirmed by A/B: 16-wave
// (round 7, DS-saturated) and 2-wave (round 18, latency-exposed) variants
// both slower. No setprio (NaN'd in round 13/14). XCD swizzle bh = id&31.
// ---------------------------------------------------------------------------
static __device__ __forceinline__ void plswap(unsigned& a, unsigned& b) {
    asm("v_permlane32_swap_b32 %0, %1" : "+v"(a), "+v"(b));
}

template<bool DO_QK, bool DO_STAGE>
static __device__ __forceinline__ void attn_step(
    const int jt,
    const short* __restrict__ bQK,   // buffer holding K of tile jt+1
    const short* __restrict__ bPV,   // buffer holding tile jt (V at +4608)
    short* __restrict__ bW,          // buffer to receive tile jt+2
    const short* __restrict__ Kb, const short* __restrict__ Vb,
    const short8v (&qa)[4],
    f32x16& sC, f32x16& sN,
    f32x16& oacc0, f32x16& oacc1, float& rsum,
    const int r, const int c, const int l31, const int hi, const int jh)
{
    // 1. issue tile jt+2 global loads first: latency hides under compute
    float4 nk, nv;
    if (DO_STAGE) {
        nk = *(const float4*)(Kb + (size_t)((jt + 2) * 64 + r) * 64 + c * 8);
        nv = *(const float4*)(Vb + (size_t)r * L_SEQ + (jt + 2) * 64 + c * 8);
    }

    // 2. QK(jt+1) into sN - independent of softmax(jt); MFMA pipe
    if (DO_QK) {
        f32x16 s;
#pragma unroll
        for (int e = 0; e < 16; ++e) s[e] = 0.f;
#pragma unroll
        for (int dk = 0; dk < 4; ++dk) {
            const short8v kf = *(const short8v*)&bQK[(jh * 32 + l31) * 72 + dk * 16 + hi * 8];
            s = __builtin_amdgcn_mfma_f32_32x32x16_bf16(kf, qa[dk], s, 0, 0, 0);
        }
        sN = s;
    }

    // 3. softmax(jt) on sC - VALU, ready since last iteration (overlaps QK)
    float p[16];
#pragma unroll
    for (int e = 0; e < 16; ++e) p[e] = fast_exp2(sC[e]);
#pragma unroll
    for (int e = 0; e < 16; e += 4)
        rsum += (p[e] + p[e + 1]) + (p[e + 2] + p[e + 3]);

    // pack bf16 pairs (truncation; compensated by 1.0014 in inv)
    unsigned wv[8];
#pragma unroll
    for (int g = 0; g < 4; ++g) {
        wv[2 * g]     = __builtin_amdgcn_perm(__float_as_uint(p[4 * g + 1]),
                                              __float_as_uint(p[4 * g]),     0x07060302u);
        wv[2 * g + 1] = __builtin_amdgcn_perm(__float_as_uint(p[4 * g + 3]),
                                              __float_as_uint(p[4 * g + 2]), 0x07060302u);
    }
    // cross-half exchange via v_permlane32_swap_b32 (VALU, zero DS traffic)
    unsigned s00 = wv[0], s02 = wv[2]; plswap(s00, s02);
    unsigned s01 = wv[1], s03 = wv[3]; plswap(s01, s03);
    unsigned s10 = wv[4], s12 = wv[6]; plswap(s10, s12);
    unsigned s11 = wv[5], s13 = wv[7]; plswap(s11, s13);

    u32x4 f0, f1;
    f0[0] = s00;  f0[1] = s01;  f0[2] = s02;  f0[3] = s03;
    f1[0] = s10;  f1[1] = s11;  f1[2] = s12;  f1[3] = s13;
    const short8v pa0 = __builtin_bit_cast(short8v, f0);
    const short8v pa1 = __builtin_bit_cast(short8v, f1);

    // 4. PV(jt): B = V rows from bPV (V at short offset 4608)
    const short* Vc = bPV + 4608;
    {
        const short8v vf00 = *(const short8v*)&Vc[(0 * 32 + l31) * 72 + jh * 32 + 0 * 16 + hi * 8];
        const short8v vf01 = *(const short8v*)&Vc[(1 * 32 + l31) * 72 + jh * 32 + 0 * 16 + hi * 8];
        oacc0 = __builtin_amdgcn_mfma_f32_32x32x16_bf16(pa0, vf00, oacc0, 0, 0, 0);
        oacc1 = __builtin_amdgcn_mfma_f32_32x32x16_bf16(pa0, vf01, oacc1, 0, 0, 0);
        const short8v vf10 = *(const short8v*)&Vc[(0 * 32 + l31) * 72 + jh * 32 + 1 * 16 + hi * 8];
        const short8v vf11 = *(const short8v*)&Vc[(1 * 32 + l31) * 72 + jh * 32 + 1 * 16 + hi * 8];
        oacc0 = __builtin_amdgcn_mfma_f32_32x32x16_bf16(pa1, vf10, oacc0, 0, 0, 0);
        oacc1 = __builtin_amdgcn_mfma_f32_32x32x16_bf16(pa1, vf11, oacc1, 0, 0, 0);
    }

    // 5. drain prefetch into bW; 6. single per-tile barrier publishes it
    if (DO_STAGE) {
        *(float4*)&bW[r * 72 + c * 8]        = nk;
        *(float4*)&bW[4608 + r * 72 + c * 8] = nv;
    }
    __syncthreads();
}

__global__ __launch_bounds__(512, 4) void attn_mfma(
    const short* __restrict__ Qws, const short* __restrict__ Kws,
    const short* __restrict__ Vws, short* __restrict__ ao)
{
    const int bh = blockIdx.x & 31;
    const int b  = bh >> 3;
    const int h  = bh & 7;
    const int i0 = (blockIdx.x >> 5) * 128;

    __shared__ __align__(16) char smem[55296];
    // 3 buffers at bytes 0/18432/36864: K [64 j][72 d], V^T [64 d][72 j] at
    // +9216 bytes. Epilogue overlays (phase-separated by barriers):
    // Opart 32768B at 0, Rp 512B at 32768, then Old [128][68] f32 at 0.
    short* B0 = (short*)smem;
    short* B1 = (short*)(smem + 18432);
    short* B2 = (short*)(smem + 36864);
    float* Old = (float*)smem;

    const int t    = threadIdx.x;
    const int w    = t >> 6;               // 0..7
    const int lane = t & 63;
    const int l31  = lane & 31;
    const int hi   = lane >> 5;            // half-wave
    const int gi   = w >> 1;               // i-group 0..3 (32 rows each)
    const int jh   = w & 1;                // j-half of the 64-j tile

    const short* Qb = Qws + (size_t)bh * L_SEQ * 64;
    const short* Kb = Kws + (size_t)bh * L_SEQ * 64;
    const short* Vb = Vws + (size_t)bh * 64 * L_SEQ;

    // Persistent Q fragments (B-operand: col=i=l31, k=d=dk*16+hi*8+e)
    short8v qa[4];
#pragma unroll
    for (int dk = 0; dk < 4; ++dk)
        qa[dk] = *(const short8v*)(Qb + (size_t)(i0 + gi * 32 + l31) * 64 + dk * 16 + hi * 8);

    f32x16 oacc0, oacc1;                    // O partial, d-halves 0..31 / 32..63
#pragma unroll
    for (int e = 0; e < 16; ++e) { oacc0[e] = 0.f; oacc1[e] = 0.f; }
    float rsum = 0.f;

    const int r = t >> 3, c = t & 7;        // staging: 64 rows x 8 float4 cols

    // Prologue: stage tiles 0 and 1 into B0 and B1
    {
        const float4 k0 = *(const float4*)(Kb + (size_t)r * 64 + c * 8);
        const float4 v0 = *(const float4*)(Vb + (size_t)r * L_SEQ + c * 8);
        const float4 k1 = *(const float4*)(Kb + (size_t)(64 + r) * 64 + c * 8);
        const float4 v1 = *(const float4*)(Vb + (size_t)r * L_SEQ + 64 + c * 8);
        *(float4*)&B0[r * 72 + c * 8]        = k0;
        *(float4*)&B0[4608 + r * 72 + c * 8] = v0;
        *(float4*)&B1[r * 72 + c * 8]        = k1;
        *(float4*)&B1[4608 + r * 72 + c * 8] = v1;
    }
    __syncthreads();

    // QK(0) from B0 into sA
    f32x16 sA, sB;
#pragma unroll
    for (int e = 0; e < 16; ++e) sA[e] = 0.f;
#pragma unroll
    for (int dk = 0; dk < 4; ++dk) {
        const short8v kf = *(const short8v*)&B0[(jh * 32 + l31) * 72 + dk * 16 + hi * 8];
        sA = __builtin_amdgcn_mfma_f32_32x32x16_bf16(kf, qa[dk], sA, 0, 0, 0);
    }

    // Main loop: t = 0..29 (period 6: buffer cycle x3, S ping-pong x2)
    for (int p6 = 0; p6 < 5; ++p6) {
        attn_step<true, true>(p6 * 6 + 0, B1, B0, B2, Kb, Vb, qa, sA, sB, oacc0, oacc1, rsum, r, c, l31, hi, jh);
        attn_step<true, true>(p6 * 6 + 1, B2, B1, B0, Kb, Vb, qa, sB, sA, oacc0, oacc1, rsum, r, c, l31, hi, jh);
        attn_step<true, true>(p6 * 6 + 2, B0, B2, B1, Kb, Vb, qa, sA, sB, oacc0, oacc1, rsum, r, c, l31, hi, jh);
        attn_step<true, true>(p6 * 6 + 3, B1, B0, B2, Kb, Vb, qa, sB, sA, oacc0, oacc1, rsum, r, c, l31, hi, jh);
        attn_step<true, true>(p6 * 6 + 4, B2, B1, B0, Kb, Vb, qa, sA, sB, oacc0, oacc1, rsum, r, c, l31, hi, jh);
        attn_step<true, true>(p6 * 6 + 5, B0, B2, B1, Kb, Vb, qa, sB, sA, oacc0, oacc1, rsum, r, c, l31, hi, jh);
    }
    // t = 30: QK(31), no stage(32). t = 31: no QK, no stage.
    attn_step<true,  false>(30, B1, B0, B2, Kb, Vb, qa, sA, sB, oacc0, oacc1, rsum, r, c, l31, hi, jh);
    attn_step<false, false>(31, B2, B1, B0, Kb, Vb, qa, sB, sA, oacc0, oacc1, rsum, r, c, l31, hi, jh);

    // ---- epilogue: combine j-halves (partner waves w, w^1), normalize ----
    const float r2 = rsum + __shfl_xor(rsum, 32, 64);

    float* Opart = (float*)smem;                 // [gi][8 chunks][64 lanes][4]
    float* Rp    = (float*)(smem + 32768);       // [128]

    if (jh == 1) {
#pragma unroll
        for (int q = 0; q < 4; ++q) {
            float4 a = { oacc0[4 * q], oacc0[4 * q + 1], oacc0[4 * q + 2], oacc0[4 * q + 3] };
            float4 bq = { oacc1[4 * q], oacc1[4 * q + 1], oacc1[4 * q + 2], oacc1[4 * q + 3] };
            *(float4*)&Opart[gi * 2048 + q * 256 + lane * 4]         = a;
            *(float4*)&Opart[gi * 2048 + (4 + q) * 256 + lane * 4]   = bq;
        }
        if (hi == 0) Rp[gi * 32 + l31] = r2;
    }
    __syncthreads();

    if (jh == 0) {
#pragma unroll
        for (int q = 0; q < 4; ++q) {
            const float4 a  = *(const float4*)&Opart[gi * 2048 + q * 256 + lane * 4];
            const float4 bq = *(const float4*)&Opart[gi * 2048 + (4 + q) * 256 + lane * 4];
            oacc0[4 * q] += a.x;  oacc0[4 * q + 1] += a.y;
            oacc0[4 * q + 2] += a.z; oacc0[4 * q + 3] += a.w;
            oacc1[4 * q] += bq.x; oacc1[4 * q + 1] += bq.y;
            oacc1[4 * q + 2] += bq.z; oacc1[4 * q + 3] += bq.w;
        }
        const float rt  = r2 + Rp[gi * 32 + l31];
        const float inv = 1.0014f / rt;          // truncation-bias comp.
#pragma unroll
        for (int e = 0; e < 16; ++e) {
            const int rowi = (e & 3) + 8 * (e >> 2) + 4 * hi;
            const float iv = __shfl(inv, rowi, 64);
            oacc0[e] *= iv;
            oacc1[e] *= iv;
        }
    }
    __syncthreads();   // Opart reads done before Old overlay writes

    if (jh == 0) {
#pragma unroll
        for (int e = 0; e < 16; ++e) {
            const int rowi = (e & 3) + 8 * (e >> 2) + 4 * hi;
            Old[(gi * 32 + rowi) * 68 + l31]      = oacc0[e];
            Old[(gi * 32 + rowi) * 68 + 32 + l31] = oacc1[e];
        }
    }
    __syncthreads();

    // vectorized bf16 store
#pragma unroll
    for (int p = 0; p < 4; ++p) {
        const int idx = p * 512 + t;
        const int i = idx >> 4, c4 = idx & 15;
        const float4 v = *(const float4*)&Old[i * 68 + c4 * 4];
        short4 s;
        s.x = f2b(v.x); s.y = f2b(v.y); s.z = f2b(v.z); s.w = f2b(v.w);
        *(short4*)&ao[((size_t)b * L_SEQ + i0 + i) * KDIM + h * 64 + c4 * 4] = s;
    }
}

// ---------------------------------------------------------------------------
extern "C" void kernel_launch(void* const* d_in, const int* in_sizes, int n_in,
                              void* d_out, int out_size, void* d_ws, size_t ws_size,
                              hipStream_t stream)
{
    const float* x     = (const float*)d_in[0];   // [4][512][2048]
    const float* w_qkv = (const float*)d_in[1];   // [1536][512]
    const float* w_out = (const float*)d_in[2];   // [512][512]
    const float* b_out = (const float*)d_in[3];   // [512]
    float* out = (float*)d_out;                   // [4][512][2048]

    char* ws = (char*)d_ws;
    short* xT    = (short*)ws;                      ws += (size_t)4 * L_SEQ * KDIM * 2;
    short* wq_bf = (short*)ws;                      ws += (size_t)1536 * 512 * 2;
    short* wo_bf = (short*)ws;                      ws += (size_t)512 * 512 * 2;
    short* Qws   = (short*)ws;                      ws += (size_t)32 * L_SEQ * 64 * 2;
    short* Kws   = (short*)ws;                      ws += (size_t)32 * L_SEQ * 64 * 2;
    short* Vws   = (short*)ws;                      ws += (size_t)32 * L_SEQ * 64 * 2;
    short* ao    = (short*)ws;

    dim3 blk(256);
    prep       <<<dim3(2048), blk, 0, stream>>>(w_qkv, w_out, x, wq_bf, wo_bf, xT);
    gemm_bt<0> <<<dim3(768), blk, 0, stream>>>(wq_bf, xT, nullptr, Qws, Kws, Vws, nullptr);
    attn_mfma  <<<dim3(512), dim3(512), 0, stream>>>(Qws, Kws, Vws, ao);
    gemm_bt<1> <<<dim3(512), blk, 0, stream>>>(wo_bf, ao, b_out, nullptr, nullptr, nullptr, out);
}